// Round 3
// baseline (122.108 us; speedup 1.0000x reference)
//
#include <hip/hip_runtime.h>

// SpikeAmplifier: T=128, N=16, C=1, J=8192.
// Per-element (n,c,j) serial recurrence over t:
//   h = y*h + w*y;  x = x_t + h;  v = v + x;
//   s = (v >= 1);  v = s ? 0 : v;  out[t] = s;  y = s
// Pure streaming, memory-bound: 64 MiB in + 64 MiB out. Roofline ~21 us @ 6.3 TB/s.
//
// R2 change: float2 vectorization along j (dwordx2 loads/stores, 512 B/wave-instr)
// — halves vm instruction count vs dword. 65536 threads = 256 blocks x 256
// = 1 block/CU, 4 waves/CU across all 4 SIMDs. U=8 register double-buffer
// keeps 16 KiB/CU of loads in flight. Per-element arithmetic order unchanged
// (bit-exact vs reference).

#define T_STEPS 128
#define J_DIM   8192
#define NCJ     131072            // N*C*J — per-timestep element count (floats)
#define NCJ2    (NCJ / 2)         // per-timestep stride in float2 units
#define U       8                 // prefetch depth (t-steps per block)

typedef float v2f __attribute__((ext_vector_type(2)));

__global__ __launch_bounds__(256) void SpikeAmplifier_73452530696745_kernel(
    const float* __restrict__ in,    // (T, N, C, J) fp32
    const float* __restrict__ w,     // (J,) fp32
    float* __restrict__ out)         // (T, N, C, J) fp32 spikes
{
    const int idx2 = blockIdx.x * blockDim.x + threadIdx.x;  // 0 .. NCJ2-1
    const int jbase = (idx2 * 2) & (J_DIM - 1);
    const float wj0 = w[jbase];
    const float wj1 = w[jbase + 1];

    const v2f* __restrict__ in2  = (const v2f*)in;
    v2f* __restrict__       out2 = (v2f*)out;

    float h0 = 0.f, y0 = 0.f, v0 = 0.f;
    float h1 = 0.f, y1 = 0.f, v1 = 0.f;

    // Prologue: fetch block 0 (8 x dwordx2 in flight before any compute).
    v2f xbuf[U];
    int off = idx2;
    #pragma unroll
    for (int u = 0; u < U; ++u)
        xbuf[u] = __builtin_nontemporal_load(&in2[off + u * NCJ2]);

    constexpr int NBLK = T_STEPS / U;   // 16
    for (int blk = 0; blk < NBLK; ++blk) {
        // Prefetch block blk+1 before the dependent compute chain of block blk.
        v2f xnext[U];
        const int nextbase = off + U * NCJ2;
        if (blk + 1 < NBLK) {
            #pragma unroll
            for (int u = 0; u < U; ++u)
                xnext[u] = __builtin_nontemporal_load(&in2[nextbase + u * NCJ2]);
        }

        // Compute + store current block. Reference FP order per element:
        // h = y*h + w*y (exact, y in {0,1}); x = xt + h; v = v + x;
        // s = v >= 1.0f; v = s ? 0 : v.  Two independent recurrences -> 2-way ILP.
        #pragma unroll
        for (int u = 0; u < U; ++u) {
            h0 = y0 * h0 + wj0 * y0;
            h1 = y1 * h1 + wj1 * y1;
            const float x0 = xbuf[u].x + h0;
            const float x1 = xbuf[u].y + h1;
            v0 = v0 + x0;
            v1 = v1 + x1;
            const bool s0 = (v0 >= 1.0f);
            const bool s1 = (v1 >= 1.0f);
            y0 = s0 ? 1.0f : 0.0f;
            y1 = s1 ? 1.0f : 0.0f;
            v0 = s0 ? 0.0f : v0;
            v1 = s1 ? 0.0f : v1;
            v2f yv; yv.x = y0; yv.y = y1;
            __builtin_nontemporal_store(yv, &out2[off + u * NCJ2]);
        }

        off = nextbase;
        #pragma unroll
        for (int u = 0; u < U; ++u) xbuf[u] = xnext[u];
    }
}

extern "C" void kernel_launch(void* const* d_in, const int* in_sizes, int n_in,
                              void* d_out, int out_size, void* d_ws, size_t ws_size,
                              hipStream_t stream) {
    const float* in  = (const float*)d_in[0];   // (T,N,C,J) = 16,777,216 floats
    const float* w   = (const float*)d_in[1];   // (J,) = 8192 floats
    float*       out = (float*)d_out;           // (T,N,C,J)

    // 65536 threads = 256 blocks x 256 = 1 block/CU, 4 waves/CU (all 4 SIMDs).
    SpikeAmplifier_73452530696745_kernel<<<NCJ2 / 256, 256, 0, stream>>>(in, w, out);
}

// Round 4
// 117.083 us; speedup vs baseline: 1.0429x; 1.0429x over previous
//
#include <hip/hip_runtime.h>

// SpikeAmplifier: T=128, N=16, C=1, J=8192.
// Per-element (n,c,j) serial recurrence over t:
//   h = y*h + w*y;  x = x_t + h;  v = v + x;
//   s = (v >= 1);  v = s ? 0 : v;  out[t] = s;  y = s
// Pure streaming, memory-bound: 64 MiB in + 64 MiB out. Roofline ~21 us @ 6.3 TB/s.
//
// R3 change: float4 (dwordx4, 1 KiB/wave-instr) — the m13 6.3 TB/s copy recipe.
// 32768 float4 columns = 512 blocks x 64 threads = 2 waves/CU over all 256 CUs.
// U=8 register double-buffer -> 16 KiB/CU reads in flight (>9 KiB needed at
// ~900 cy HBM latency). 4 independent recurrences/thread = 4-way ILP.
// Per-element arithmetic order unchanged (bit-exact vs reference).

#define T_STEPS 128
#define J_DIM   8192
#define NCJ     131072            // N*C*J — per-timestep element count (floats)
#define NCJ4    (NCJ / 4)         // per-timestep stride in float4 units (32768)
#define U       8                 // prefetch depth (t-steps per block)

typedef float v4f __attribute__((ext_vector_type(4)));

__global__ __launch_bounds__(64) void SpikeAmplifier_73452530696745_kernel(
    const float* __restrict__ in,    // (T, N, C, J) fp32
    const float* __restrict__ w,     // (J,) fp32
    float* __restrict__ out)         // (T, N, C, J) fp32 spikes
{
    const int idx4 = blockIdx.x * blockDim.x + threadIdx.x;  // 0 .. NCJ4-1
    const int jbase = (idx4 * 4) & (J_DIM - 1);
    const v4f wv = *(const v4f*)&w[jbase];

    const v4f* __restrict__ in4  = (const v4f*)in;
    v4f* __restrict__       out4 = (v4f*)out;

    v4f h = {0.f, 0.f, 0.f, 0.f};
    v4f y = {0.f, 0.f, 0.f, 0.f};
    v4f v = {0.f, 0.f, 0.f, 0.f};

    // Prologue: fetch block 0 (8 x dwordx4 in flight before any compute).
    v4f xbuf[U];
    int off = idx4;
    #pragma unroll
    for (int u = 0; u < U; ++u)
        xbuf[u] = __builtin_nontemporal_load(&in4[off + u * NCJ4]);

    constexpr int NBLK = T_STEPS / U;   // 16
    for (int blk = 0; blk < NBLK; ++blk) {
        // Prefetch block blk+1 before the dependent compute chain of block blk.
        v4f xnext[U];
        const int nextbase = off + U * NCJ4;
        if (blk + 1 < NBLK) {
            #pragma unroll
            for (int u = 0; u < U; ++u)
                xnext[u] = __builtin_nontemporal_load(&in4[nextbase + u * NCJ4]);
        }

        // Compute + store current block. Reference FP order per element:
        // h = y*h + w*y (exact, y in {0,1}); x = xt + h; v = v + x;
        // s = v >= 1.0f; v = s ? 0 : v.  4 independent lanes -> 4-way ILP.
        #pragma unroll
        for (int u = 0; u < U; ++u) {
            v4f yv;
            #pragma unroll
            for (int e = 0; e < 4; ++e) {
                h[e] = y[e] * h[e] + wv[e] * y[e];
                const float x = xbuf[u][e] + h[e];
                v[e] = v[e] + x;
                const bool s = (v[e] >= 1.0f);
                y[e] = s ? 1.0f : 0.0f;
                v[e] = s ? 0.0f : v[e];
                yv[e] = y[e];
            }
            __builtin_nontemporal_store(yv, &out4[off + u * NCJ4]);
        }

        off = nextbase;
        #pragma unroll
        for (int u = 0; u < U; ++u) xbuf[u] = xnext[u];
    }
}

extern "C" void kernel_launch(void* const* d_in, const int* in_sizes, int n_in,
                              void* d_out, int out_size, void* d_ws, size_t ws_size,
                              hipStream_t stream) {
    const float* in  = (const float*)d_in[0];   // (T,N,C,J) = 16,777,216 floats
    const float* w   = (const float*)d_in[1];   // (J,) = 8192 floats
    float*       out = (float*)d_out;           // (T,N,C,J)

    // 32768 threads = 512 blocks x 64 = 2 single-wave blocks per CU, all CUs covered.
    SpikeAmplifier_73452530696745_kernel<<<NCJ4 / 64, 64, 0, stream>>>(in, w, out);
}